// Round 6
// baseline (1274.409 us; speedup 1.0000x reference)
//
#include <hip/hip_runtime.h>
#include <math.h>

#define BATCH 131072

// ---------------------------------------------------------------------------
// Fused GEMM + optional input BN-affine/lrelu + optional BN stats accumulate.
// C[r,n] = sum_k f(A[r,k]) * W[k,n] + bias[n],  f = lrelu(x*sc+sh) or identity
//
// R6: double-buffered LDS (KS=16), register-prefetch pipeline:
//   issue loads(kc+1) -> barrier -> compute(kc) -> commit(kc+1 -> buf^1)
// One barrier per chunk; staging regs kept tiny (<= 6 float4) so acc never
// spills (R3 lesson: 48 staging regs + unroll-2 evicted acc -> 1.1GB scratch).
// A-tile row-major [MT][KS] with float4-group XOR swizzle (c4 ^ (row/TM)&3):
// fragment reads are conflict-free ds_read_b128. BN finalize fused in prologue.
// ---------------------------------------------------------------------------
template<int MT, int NT, int NSTORE, int TM, int TN, int BLK, int KS, int K,
         bool AFFINE, bool STATS>
__global__ __launch_bounds__(BLK)
void gemm_bn3(const float* __restrict__ Ain, const float* __restrict__ W,
              const float* __restrict__ bias,
              const float* __restrict__ gamma, const float* __restrict__ beta,
              const double* __restrict__ prevSum, const double* __restrict__ prevSq,
              float* __restrict__ Xout_g,
              double* __restrict__ outSum, double* __restrict__ outSq)
{
    constexpr int KC   = (K + KS - 1) / KS;
    constexpr bool TAIL = (K % KS) != 0;
    constexpr int CPR  = KS / 4;              // float4 groups per A row (=4)
    constexpr int NCG  = NT / TN;
    constexpr int RG   = MT / TM;
    constexpr int NH   = TN / 4;
    constexpr int AL4  = MT * KS / 4 / BLK;   // A float4 loads / thread / chunk
    constexpr bool BVEC = (NT == NSTORE) && (KS * NT / 4 >= BLK);
    constexpr int BL4  = BVEC ? (KS * NT / 4 / BLK) : 1;
    constexpr int BLS  = BVEC ? 1 : (KS * NT / BLK);
    constexpr int HF   = (TM >= 8) ? 8 : TM;
    static_assert(NCG * RG == BLK, "thread mapping");
    static_assert(MT * KS / 4 % BLK == 0, "A staging divisibility");
    static_assert(CPR == 4, "swizzle assumes 4 groups");
    static_assert(!STATS || RG <= KS, "stats scratch fits Bs");

    __shared__ float As[2][MT][KS];
    __shared__ float Bs[2][KS][NT];
    __shared__ float scs[AFFINE ? K : 1];
    __shared__ float shs[AFFINE ? K : 1];

    const int tid = threadIdx.x;
    const int r0  = blockIdx.x * MT;
    const int tx  = tid % NCG;
    const int ty  = tid / NCG;
    const int key = ty & 3;

    // fused BN finalize (redundant per block, trivial)
    if constexpr (AFFINE) {
        for (int i = tid; i < K; i += BLK) {
            const double inv = 1.0 / (double)BATCH;
            double mu  = prevSum[i] * inv;
            double var = prevSq[i] * inv - mu * mu;
            double s   = (double)gamma[i] / sqrt(var + 1e-5);
            scs[i] = (float)s;
            shs[i] = (float)((double)beta[i] - mu * s);
        }
    }

    float acc[TM][TN] = {};
    float4 aReg[AL4];
    float4 bReg[BVEC ? BL4 : 1];
    float  bRegS[BVEC ? 1 : BLS];

    auto issue = [&](int kc) {
        #pragma unroll
        for (int l = 0; l < AL4; ++l) {
            int idx = tid + l * BLK;
            int row = idx / CPR;
            int c4  = idx % CPR;
            int gk  = kc * KS + c4 * 4;
            const float* gp = Ain + (size_t)(r0 + row) * K + gk;
            if constexpr (!TAIL) {
                aReg[l] = *reinterpret_cast<const float4*>(gp);
            } else {
                if (gk + 4 <= K) aReg[l] = *reinterpret_cast<const float4*>(gp);
                else {
                    float tt[4];
                    #pragma unroll
                    for (int c = 0; c < 4; ++c) tt[c] = (gk + c < K) ? gp[c] : 0.f;
                    aReg[l] = make_float4(tt[0], tt[1], tt[2], tt[3]);
                }
            }
        }
        if constexpr (BVEC) {
            #pragma unroll
            for (int l = 0; l < BL4; ++l) {
                int idx = tid + l * BLK;
                int kk  = idx / (NT / 4);
                int n4  = idx % (NT / 4);
                int gk  = kc * KS + kk;
                if constexpr (!TAIL)
                    bReg[l] = *reinterpret_cast<const float4*>(W + (size_t)gk * NSTORE + n4 * 4);
                else
                    bReg[l] = (gk < K)
                        ? *reinterpret_cast<const float4*>(W + (size_t)gk * NSTORE + n4 * 4)
                        : make_float4(0.f, 0.f, 0.f, 0.f);
            }
        } else {
            #pragma unroll
            for (int l = 0; l < BLS; ++l) {
                int idx = tid + l * BLK;
                int kk  = idx / NT;
                int n   = idx % NT;
                int gk  = kc * KS + kk;
                bRegS[l] = (gk < K && n < NSTORE) ? W[(size_t)gk * NSTORE + n] : 0.f;
            }
        }
    };
    auto commit = [&](int kc, int d) {
        #pragma unroll
        for (int l = 0; l < AL4; ++l) {
            int idx = tid + l * BLK;
            int row = idx / CPR;
            int c4  = idx % CPR;
            float4 v = aReg[l];
            if constexpr (AFFINE) {
                int gk = kc * KS + c4 * 4;
                float* vp = &v.x;
                #pragma unroll
                for (int c = 0; c < 4; ++c) {
                    float x = vp[c] * scs[gk + c] + shs[gk + c];
                    vp[c] = x > 0.f ? x : 0.2f * x;
                }
            }
            *reinterpret_cast<float4*>(&As[d][row][(c4 ^ ((row / TM) & 3)) * 4]) = v;
        }
        if constexpr (BVEC) {
            #pragma unroll
            for (int l = 0; l < BL4; ++l) {
                int idx = tid + l * BLK;
                *reinterpret_cast<float4*>(&Bs[d][idx / (NT / 4)][(idx % (NT / 4)) * 4]) = bReg[l];
            }
        } else {
            #pragma unroll
            for (int l = 0; l < BLS; ++l) {
                int idx = tid + l * BLK;
                Bs[d][idx / NT][idx % NT] = bRegS[l];
            }
        }
    };
    auto compute = [&](int d) {
        #pragma unroll
        for (int k4 = 0; k4 < CPR; ++k4) {
            const int pf = (k4 ^ key) * 4;
            float4 bq[4][NH];
            #pragma unroll
            for (int kk = 0; kk < 4; ++kk)
                #pragma unroll
                for (int h = 0; h < NH; ++h)
                    bq[kk][h] = *reinterpret_cast<const float4*>(
                        &Bs[d][k4 * 4 + kk][h * (NCG * 4) + tx * 4]);
            #pragma unroll
            for (int hf = 0; hf < TM / HF; ++hf) {
                float4 a4[HF];
                #pragma unroll
                for (int i = 0; i < HF; ++i)
                    a4[i] = *reinterpret_cast<const float4*>(
                        &As[d][ty * TM + hf * HF + i][pf]);
                #pragma unroll
                for (int kk = 0; kk < 4; ++kk)
                    #pragma unroll
                    for (int i = 0; i < HF; ++i) {
                        const float av = (&a4[i].x)[kk];
                        const float* bp = &bq[kk][0].x;
                        #pragma unroll
                        for (int j = 0; j < TN; ++j)
                            acc[hf * HF + i][j] = fmaf(av, bp[j], acc[hf * HF + i][j]);
                    }
            }
        }
    };

    // ---- pipeline --------------------------------------------------------
    issue(0);
    __syncthreads();              // scs/shs visible before first transform
    commit(0, 0);
    #pragma unroll 1
    for (int kc = 0; kc < KC; ++kc) {
        if (kc + 1 < KC) issue(kc + 1);
        __syncthreads();          // commit(kc) visible to all waves
        compute(kc & 1);
        if (kc + 1 < KC) commit(kc + 1, (kc + 1) & 1);
    }

    // ---- epilogue: bias, store, BN stats ---------------------------------
    float bc[TN];
    #pragma unroll
    for (int j = 0; j < TN; ++j) {
        int gc = (j >> 2) * (NCG * 4) + tx * 4 + (j & 3);
        bc[j] = (gc < NSTORE) ? bias[gc] : 0.f;
    }
    float psum[TN] = {}, psq[TN] = {};
    #pragma unroll
    for (int i = 0; i < TM; ++i) {
        int row = r0 + ty * TM + i;
        float x[TN];
        #pragma unroll
        for (int j = 0; j < TN; ++j) {
            x[j] = acc[i][j] + bc[j];
            if (STATS) { psum[j] += x[j]; psq[j] += x[j] * x[j]; }
        }
        if constexpr (NT == NSTORE) {
            #pragma unroll
            for (int h = 0; h < NH; ++h) {
                float4 v = make_float4(x[h*4], x[h*4+1], x[h*4+2], x[h*4+3]);
                *reinterpret_cast<float4*>(
                    &Xout_g[(size_t)row * NSTORE + h * (NCG * 4) + tx * 4]) = v;
            }
        } else {
            #pragma unroll
            for (int j = 0; j < TN; ++j) {
                int gc = (j >> 2) * (NCG * 4) + tx * 4 + (j & 3);
                if (gc < NSTORE) Xout_g[(size_t)row * NSTORE + gc] = x[j];
            }
        }
    }
    if constexpr (STATS) {
        __syncthreads();          // all compute done; Bs reusable as scratch
        float* S1 = &Bs[0][0][0];
        float* S2 = S1 + RG * NT;
        #pragma unroll
        for (int j = 0; j < TN; ++j) {
            int gc = (j >> 2) * (NCG * 4) + tx * 4 + (j & 3);
            S1[ty * NT + gc] = psum[j];
            S2[ty * NT + gc] = psq[j];
        }
        __syncthreads();
        if (tid < NT) {
            double s = 0.0, q = 0.0;
            #pragma unroll 4
            for (int t = 0; t < RG; ++t) {
                s += (double)S1[t * NT + tid];
                q += (double)S2[t * NT + tid];
            }
            atomicAdd(&outSum[tid], s);
            atomicAdd(&outSq[tid], q);
        }
    }
}

// ---------------------------------------------------------------------------
// Gumbel top-K scan: 256 rows/block, one thread per row, double-buffered u
// tile with register prefetch.
// argmax(softmax((masked+noise)/T)) == argmax over unmasked of (logit+noise),
// noise = -log(-log(u)); strict > keeps first index (jnp.argmax tie-break).
// ---------------------------------------------------------------------------
__global__ __launch_bounds__(256)
void gumbel_topk(const float* __restrict__ logits, const float* __restrict__ u,
                 float* __restrict__ out)
{
    __shared__ __align__(16) float lg[256 * 25];
    __shared__ __align__(16) float us[2][256 * 25];
    const int tid = threadIdx.x;
    const int r0  = blockIdx.x * 256;

    {
        const float4* src = reinterpret_cast<const float4*>(logits + (size_t)r0 * 25);
        float4* dst = reinterpret_cast<float4*>(lg);
        #pragma unroll
        for (int l = 0; l < 7; ++l) {
            int i = tid + l * 256;
            if (i < 1600) dst[i] = src[i];
        }
        const float4* u0 = reinterpret_cast<const float4*>(u + (size_t)r0 * 25);
        float4* d0 = reinterpret_cast<float4*>(us[0]);
        #pragma unroll
        for (int l = 0; l < 7; ++l) {
            int i = tid + l * 256;
            if (i < 1600) d0[i] = u0[i];
        }
    }
    __syncthreads();

    float myl[25];
    #pragma unroll
    for (int j = 0; j < 25; ++j) myl[j] = lg[tid * 25 + j];

    unsigned mask = 0x1FFFFFFu;  // 25 ones
    for (int it = 0; it < 15; ++it) {
        const int cur = it & 1;
        float4 t[7];
        const bool have = (it + 1) < 15;
        if (have) {
            const float4* un = reinterpret_cast<const float4*>(
                u + ((size_t)(it + 1) * BATCH + r0) * 25);
            #pragma unroll
            for (int l = 0; l < 7; ++l) {
                int i = tid + l * 256;
                if (i < 1600) t[l] = un[i];
            }
        }

        float best = -INFINITY;
        int bj = 0;
        #pragma unroll
        for (int j = 0; j < 25; ++j) {
            float uu = us[cur][tid * 25 + j];
            float nz = -logf(-logf(uu));   // accurate logf: argmax must match np fp32
            float v  = myl[j] + nz;
            v = ((mask >> j) & 1u) ? v : -INFINITY;
            if (v > best) { best = v; bj = j; }
        }
        mask &= ~(1u << bj);
        out[(size_t)(r0 + tid) * 15 + it] = (float)bj / 24.0f;

        if (have) {
            float4* dn = reinterpret_cast<float4*>(us[cur ^ 1]);
            #pragma unroll
            for (int l = 0; l < 7; ++l) {
                int i = tid + l * 256;
                if (i < 1600) dn[i] = t[l];
            }
        }
        __syncthreads();
    }
}

extern "C" void kernel_launch(void* const* d_in, const int* in_sizes, int n_in,
                              void* d_out, int out_size, void* d_ws, size_t ws_size,
                              hipStream_t stream)
{
    (void)in_sizes; (void)n_in; (void)out_size; (void)ws_size;
    const float* z   = (const float*)d_in[0];
    const float* u   = (const float*)d_in[1];
    const float* W1  = (const float*)d_in[2];
    const float* b1  = (const float*)d_in[3];
    const float* g1  = (const float*)d_in[4];
    const float* be1 = (const float*)d_in[5];
    const float* W2  = (const float*)d_in[6];
    const float* b2  = (const float*)d_in[7];
    const float* g2  = (const float*)d_in[8];
    const float* be2 = (const float*)d_in[9];
    const float* W3  = (const float*)d_in[10];
    const float* b3  = (const float*)d_in[11];
    const float* g3  = (const float*)d_in[12];
    const float* be3 = (const float*)d_in[13];
    const float* W4  = (const float*)d_in[14];
    const float* b4  = (const float*)d_in[15];
    float* out = (float*)d_out;

    char* ws = (char*)d_ws;
    float* X2     = (float*)ws;                                  // B*256 f32 (later logits)
    float* XA     = (float*)(ws + (size_t)134217728);            // B*128 f32 (X1, then X3)
    char*  statb  = ws + (size_t)134217728 + (size_t)67108864;
    double* sum1 = (double*)statb;      double* sq1 = sum1 + 128;
    double* sum2 = sq1 + 128;           double* sq2 = sum2 + 256;
    double* sum3 = sq2 + 256;           double* sq3 = sum3 + 128;
    float* logits = X2;                 // X2 region dead after P3

    (void)hipMemsetAsync(statb, 0, 1024 * sizeof(double), stream);

    // P1: z[B,50] @ W1[50,128] -> X1 (XA) + stats1.  KS=16 (tail), LDS 48KB
    gemm_bn3<256,128,128, 16,8, 256, 16, 50, false, true>
        <<<BATCH/256, 256, 0, stream>>>(z, W1, b1, nullptr, nullptr,
                                        nullptr, nullptr, XA, sum1, sq1);

    // P2: lrelu(bn(X1)) @ W2[128,256] -> X2 + stats2.  LDS 49KB
    gemm_bn3<128,256,256, 16,8, 256, 16, 128, true, true>
        <<<BATCH/128, 256, 0, stream>>>(XA, W2, b2, g1, be1,
                                        sum1, sq1, X2, sum2, sq2);

    // P3: lrelu(bn(X2)) @ W3[256,128] -> X3 (XA) + stats3.  LDS 50KB
    gemm_bn3<256,128,128, 16,8, 256, 16, 256, true, true>
        <<<BATCH/256, 256, 0, stream>>>(X2, W3, b3, g2, be2,
                                        sum2, sq2, XA, sum3, sq3);

    // P3b: lrelu(bn(X3)) @ W4[128,25] -> logits.  LDS 37KB
    gemm_bn3<256,32,25, 4,8, 256, 16, 128, true, false>
        <<<BATCH/256, 256, 0, stream>>>(XA, W4, b4, g3, be3,
                                        sum3, sq3, logits, nullptr, nullptr);

    // P4: gumbel top-15 scan
    gumbel_topk<<<BATCH/256, 256, 0, stream>>>(logits, u, out);
}

// Round 9
// 856.618 us; speedup vs baseline: 1.4877x; 1.4877x over previous
//
#include <hip/hip_runtime.h>
#include <math.h>
#include <stdint.h>

#define BATCH 131072

// direct HBM->LDS async copy, 16B per lane. LDS dest must be linear in lane
// order (wave-uniform base + lane*16); global src is per-lane (m173 pattern).
typedef __attribute__((address_space(3))) uint32_t lds_u32_t;
typedef const __attribute__((address_space(1))) uint32_t gbl_u32_t;
__device__ __forceinline__ void gload16(const float* g, float* l) {
    __builtin_amdgcn_global_load_lds((gbl_u32_t*)g, (lds_u32_t*)l, 16, 0, 0);
}

// ---------------------------------------------------------------------------
// Pure GEMM + bias + optional BN stats. NO input transform (done by bn_lrelu
// pass), NO staging registers (global_load_lds direct-to-LDS, double-buffered:
//   issue loads(kc+1)->buf^1 ; compute(kc, buf) ; barrier (drains vmcnt)
// A-tile [MT][KS] with float4-group XOR swizzle applied on the GLOBAL SOURCE
// address (LDS stays lane-linear); compute reads As[row][(k4^(ty&3))*4] as
// conflict-free ds_read_b128. R3/R6 lesson: zero regs live across compute.
// ---------------------------------------------------------------------------
template<int MT, int NT, int NSTORE, int TM, int TN, int BLK, int KS, int K,
         bool STATS, bool BFULL>
__global__ __launch_bounds__(BLK)
void gemm_ld(const float* __restrict__ Ain, const float* __restrict__ W,
             const float* __restrict__ bias, float* __restrict__ Xout,
             double* __restrict__ outSum, double* __restrict__ outSq)
{
    constexpr int KC  = K / KS;
    constexpr int CPR = KS / 4;               // float4 groups per A row (=4)
    constexpr int NCG = NT / TN;
    constexpr int RG  = MT / TM;
    constexpr int NH  = TN / 4;
    constexpr int AL4 = MT * KS / 4 / BLK;
    constexpr int BL4 = BFULL ? 1 : (KS * NT / 4 / BLK);
    constexpr int HF  = (TM >= 8) ? 8 : TM;
    static_assert(K % KS == 0, "no K tail in gemm_ld");
    static_assert(NCG * RG == BLK, "thread mapping");
    static_assert((MT * KS / 4) % BLK == 0, "A staging divisibility");
    static_assert(CPR == 4, "swizzle assumes 4 groups/row");
    static_assert(!STATS || 2 * RG * NT <= 2 * KS * NT, "stats scratch fits Bs");

    __shared__ float As[2][MT][KS];
    __shared__ float Bs[BFULL ? 1 : 2][KS][NT];
    __shared__ float Bf[BFULL ? K : 1][BFULL ? NT : 1];

    const int tid = threadIdx.x;
    const int r0  = blockIdx.x * MT;
    const int tx  = tid % NCG;
    const int ty  = tid / NCG;
    const int key = ty & 3;

    float acc[TM][TN] = {};

    auto stageA = [&](int kc, int d) {
        #pragma unroll
        for (int l = 0; l < AL4; ++l) {
            int idx = tid + l * BLK;
            int row = idx / CPR;
            int p   = idx % CPR;
            int c4  = p ^ ((row / TM) & 3);            // inverse swizzle on source
            gload16(Ain + (size_t)(r0 + row) * K + kc * KS + c4 * 4,
                    &As[d][0][0] + idx * 4);           // lane-linear LDS dest
        }
    };
    auto stageB = [&](int kc, int d) {
        #pragma unroll
        for (int l = 0; l < BL4; ++l) {
            int idx = tid + l * BLK;
            int kk  = idx / (NT / 4);
            int n4  = idx % (NT / 4);
            gload16(W + (size_t)(kc * KS + kk) * NSTORE + n4 * 4,
                    &Bs[d][0][0] + idx * 4);
        }
    };
    auto compute = [&](int kb, int d) {
        #pragma unroll
        for (int k4 = 0; k4 < CPR; ++k4) {
            const int pf = (k4 ^ key) * 4;
            float4 bq[4][NH];
            #pragma unroll
            for (int kk = 0; kk < 4; ++kk)
                #pragma unroll
                for (int h = 0; h < NH; ++h)
                    bq[kk][h] = *reinterpret_cast<const float4*>(
                        BFULL ? &Bf[kb + k4 * 4 + kk][h * (NCG * 4) + tx * 4]
                              : &Bs[d][k4 * 4 + kk][h * (NCG * 4) + tx * 4]);
            #pragma unroll
            for (int hf = 0; hf < TM / HF; ++hf) {
                float4 a4[HF];
                #pragma unroll
                for (int i = 0; i < HF; ++i)
                    a4[i] = *reinterpret_cast<const float4*>(
                        &As[d][ty * TM + hf * HF + i][pf]);
                #pragma unroll
                for (int kk = 0; kk < 4; ++kk)
                    #pragma unroll
                    for (int i = 0; i < HF; ++i) {
                        const float av = (&a4[i].x)[kk];
                        const float* bp = &bq[kk][0].x;
                        #pragma unroll
                        for (int j = 0; j < TN; ++j)
                            acc[hf * HF + i][j] = fmaf(av, bp[j], acc[hf * HF + i][j]);
                    }
            }
        }
    };

    // ---- prologue: first chunk (+ full B prestage for BFULL)
    stageA(0, 0);
    if constexpr (BFULL) {
        constexpr int BLSF = K * NT / BLK;
        #pragma unroll
        for (int l = 0; l < BLSF; ++l) {
            int idx = tid + l * BLK;
            int kk  = idx / NT;
            int n   = idx % NT;
            Bf[kk][n] = (n < NSTORE) ? W[(size_t)kk * NSTORE + n] : 0.f;
        }
    } else {
        stageB(0, 0);
    }
    __syncthreads();

    #pragma unroll 1
    for (int kc = 0; kc < KC; ++kc) {
        const int d = kc & 1;
        if (kc + 1 < KC) {                 // async loads fly during compute
            stageA(kc + 1, d ^ 1);
            if constexpr (!BFULL) stageB(kc + 1, d ^ 1);
        }
        compute(kc * KS, d);
        __syncthreads();                   // drains vmcnt: next buf ready
    }

    // ---- epilogue: bias, store, BN stats
    float bc[TN];
    #pragma unroll
    for (int j = 0; j < TN; ++j) {
        int gc = (j >> 2) * (NCG * 4) + tx * 4 + (j & 3);
        bc[j] = (gc < NSTORE) ? bias[gc] : 0.f;
    }
    float psum[TN] = {}, psq[TN] = {};
    #pragma unroll
    for (int i = 0; i < TM; ++i) {
        int row = r0 + ty * TM + i;
        float x[TN];
        #pragma unroll
        for (int j = 0; j < TN; ++j) {
            x[j] = acc[i][j] + bc[j];
            if (STATS) { psum[j] += x[j]; psq[j] += x[j] * x[j]; }
        }
        if constexpr (NT == NSTORE) {
            #pragma unroll
            for (int h = 0; h < NH; ++h) {
                float4 v = make_float4(x[h*4], x[h*4+1], x[h*4+2], x[h*4+3]);
                *reinterpret_cast<float4*>(
                    &Xout[(size_t)row * NSTORE + h * (NCG * 4) + tx * 4]) = v;
            }
        } else {
            #pragma unroll
            for (int j = 0; j < TN; ++j) {
                int gc = (j >> 2) * (NCG * 4) + tx * 4 + (j & 3);
                if (gc < NSTORE) Xout[(size_t)row * NSTORE + gc] = x[j];
            }
        }
    }
    if constexpr (STATS) {
        __syncthreads();                   // Bs reusable as reduce scratch
        float* S1 = &Bs[0][0][0];
        float* S2 = S1 + RG * NT;
        #pragma unroll
        for (int j = 0; j < TN; ++j) {
            int gc = (j >> 2) * (NCG * 4) + tx * 4 + (j & 3);
            S1[ty * NT + gc] = psum[j];
            S2[ty * NT + gc] = psq[j];
        }
        __syncthreads();
        if (tid < NT) {
            double s = 0.0, q = 0.0;
            #pragma unroll 4
            for (int t = 0; t < RG; ++t) {
                s += (double)S1[t * NT + tid];
                q += (double)S2[t * NT + tid];
            }
            atomicAdd(&outSum[tid], s);
            atomicAdd(&outSq[tid], q);
        }
    }
}

// mu/var -> scale/shift in double (1 microblock)
__global__ void finalize_bn(const double* __restrict__ sum, const double* __restrict__ sq,
                            const float* __restrict__ g, const float* __restrict__ be,
                            float* __restrict__ sc, float* __restrict__ sh, int N)
{
    int i = threadIdx.x;
    if (i < N) {
        const double inv = 1.0 / (double)BATCH;
        double mu  = sum[i] * inv;
        double var = sq[i] * inv - mu * mu;
        double s   = (double)g[i] / sqrt(var + 1e-5);
        sc[i] = (float)s;
        sh[i] = (float)((double)be[i] - mu * s);
    }
}

// in-place X <- lrelu(X*sc + sh), vectorized float4, grid-stride (BW-bound)
__global__ __launch_bounds__(256)
void bn_lrelu(float* __restrict__ X, const float* __restrict__ sc,
              const float* __restrict__ sh, int C4, size_t n4)
{
    size_t i = (size_t)blockIdx.x * 256 + threadIdx.x;
    const size_t stride = (size_t)gridDim.x * 256;
    for (; i < n4; i += stride) {
        int c4 = (int)(i % (size_t)C4);
        float4 v = reinterpret_cast<float4*>(X)[i];
        float4 s = reinterpret_cast<const float4*>(sc)[c4];
        float4 h = reinterpret_cast<const float4*>(sh)[c4];
        float* vp = &v.x; const float* sp = &s.x; const float* hp = &h.x;
        #pragma unroll
        for (int c = 0; c < 4; ++c) {
            float x = vp[c] * sp[c] + hp[c];     // same expr as R5 (bit-identical)
            vp[c] = x > 0.f ? x : 0.2f * x;
        }
        reinterpret_cast<float4*>(X)[i] = v;
    }
}

// pad z[B,50] -> Z64[B,64] (zero cols 50..63), float4 stores
__global__ __launch_bounds__(256)
void pad_z(const float* __restrict__ z, float* __restrict__ Z64)
{
    size_t i = (size_t)blockIdx.x * 256 + threadIdx.x;
    const size_t stride = (size_t)gridDim.x * 256;
    const size_t n4 = (size_t)BATCH * 16;
    for (; i < n4; i += stride) {
        size_t row = i / 16;
        int c0 = (int)(i % 16) * 4;
        float t[4];
        #pragma unroll
        for (int c = 0; c < 4; ++c)
            t[c] = (c0 + c < 50) ? z[row * 50 + c0 + c] : 0.f;
        reinterpret_cast<float4*>(Z64)[i] = make_float4(t[0], t[1], t[2], t[3]);
    }
}

// pad W1[50,128] -> W1p[64,128] (zero rows 50..63). 1 block.
__global__ __launch_bounds__(256)
void pad_w1(const float* __restrict__ W1, float* __restrict__ W1p)
{
    for (int idx = threadIdx.x; idx < 64 * 128; idx += 256) {
        int r = idx / 128;
        W1p[idx] = (r < 50) ? W1[idx] : 0.f;
    }
}

// ---------------------------------------------------------------------------
// Gumbel top-K scan (unchanged from R5, bit-exact twice).
// ---------------------------------------------------------------------------
__global__ __launch_bounds__(256)
void gumbel_topk(const float* __restrict__ logits, const float* __restrict__ u,
                 float* __restrict__ out)
{
    __shared__ __align__(16) float lg[256 * 25];
    __shared__ __align__(16) float us[2][256 * 25];
    const int tid = threadIdx.x;
    const int r0  = blockIdx.x * 256;

    {
        const float4* src = reinterpret_cast<const float4*>(logits + (size_t)r0 * 25);
        float4* dst = reinterpret_cast<float4*>(lg);
        #pragma unroll
        for (int l = 0; l < 7; ++l) {
            int i = tid + l * 256;
            if (i < 1600) dst[i] = src[i];
        }
        const float4* u0 = reinterpret_cast<const float4*>(u + (size_t)r0 * 25);
        float4* d0 = reinterpret_cast<float4*>(us[0]);
        #pragma unroll
        for (int l = 0; l < 7; ++l) {
            int i = tid + l * 256;
            if (i < 1600) d0[i] = u0[i];
        }
    }
    __syncthreads();

    float myl[25];
    #pragma unroll
    for (int j = 0; j < 25; ++j) myl[j] = lg[tid * 25 + j];

    unsigned mask = 0x1FFFFFFu;
    for (int it = 0; it < 15; ++it) {
        const int cur = it & 1;
        float4 t[7];
        const bool have = (it + 1) < 15;
        if (have) {
            const float4* un = reinterpret_cast<const float4*>(
                u + ((size_t)(it + 1) * BATCH + r0) * 25);
            #pragma unroll
            for (int l = 0; l < 7; ++l) {
                int i = tid + l * 256;
                if (i < 1600) t[l] = un[i];
            }
        }

        float best = -INFINITY;
        int bj = 0;
        #pragma unroll
        for (int j = 0; j < 25; ++j) {
            float uu = us[cur][tid * 25 + j];
            float nz = -logf(-logf(uu));   // accurate logf: argmax must match np fp32
            float v  = myl[j] + nz;
            v = ((mask >> j) & 1u) ? v : -INFINITY;
            if (v > best) { best = v; bj = j; }
        }
        mask &= ~(1u << bj);
        out[(size_t)(r0 + tid) * 15 + it] = (float)bj / 24.0f;

        if (have) {
            float4* dn = reinterpret_cast<float4*>(us[cur ^ 1]);
            #pragma unroll
            for (int l = 0; l < 7; ++l) {
                int i = tid + l * 256;
                if (i < 1600) dn[i] = t[l];
            }
        }
        __syncthreads();
    }
}

extern "C" void kernel_launch(void* const* d_in, const int* in_sizes, int n_in,
                              void* d_out, int out_size, void* d_ws, size_t ws_size,
                              hipStream_t stream)
{
    (void)in_sizes; (void)n_in; (void)out_size; (void)ws_size;
    const float* z   = (const float*)d_in[0];
    const float* u   = (const float*)d_in[1];
    const float* W1  = (const float*)d_in[2];
    const float* b1  = (const float*)d_in[3];
    const float* g1  = (const float*)d_in[4];
    const float* be1 = (const float*)d_in[5];
    const float* W2  = (const float*)d_in[6];
    const float* b2  = (const float*)d_in[7];
    const float* g2  = (const float*)d_in[8];
    const float* be2 = (const float*)d_in[9];
    const float* W3  = (const float*)d_in[10];
    const float* b3  = (const float*)d_in[11];
    const float* g3  = (const float*)d_in[12];
    const float* be3 = (const float*)d_in[13];
    const float* W4  = (const float*)d_in[14];
    const float* b4  = (const float*)d_in[15];
    float* out = (float*)d_out;

    char* ws = (char*)d_ws;
    float* X2   = (float*)ws;                                 // 134MB: Z64 early, X2, logits late
    float* XA   = (float*)(ws + (size_t)134217728);           // 67MB: X1 (in-place X1t), X3
    char*  aux  = ws + (size_t)134217728 + (size_t)67108864;
    double* sum1 = (double*)aux;        double* sq1 = sum1 + 128;
    double* sum2 = sq1 + 128;           double* sq2 = sum2 + 256;
    double* sum3 = sq2 + 256;           double* sq3 = sum3 + 128;   // 1024 doubles = 8KB
    float* sc1 = (float*)(aux + 8192);  float* sh1 = sc1 + 128;
    float* sc2 = sh1 + 128;             float* sh2 = sc2 + 256;
    float* sc3 = sh2 + 256;             float* sh3 = sc3 + 128;     // 1056 floats
    float* W1p = (float*)(aux + 16384);                             // 32KB
    float* Z64 = X2;                    // overlays X2 region (dead until G2)
    float* logits = X2;                 // X2 region dead after G3

    (void)hipMemsetAsync(aux, 0, 1024 * sizeof(double), stream);

    // pads
    pad_z<<<2048, 256, 0, stream>>>(z, Z64);
    pad_w1<<<1, 256, 0, stream>>>(W1, W1p);

    // G1: Z64[B,64] @ W1p[64,128] -> X1 + stats1
    gemm_ld<256,128,128, 16,8, 256, 16, 64, true, false>
        <<<BATCH/256, 256, 0, stream>>>(Z64, W1p, b1, XA, sum1, sq1);
    finalize_bn<<<1, 256, 0, stream>>>(sum1, sq1, g1, be1, sc1, sh1, 128);
    bn_lrelu<<<2048, 256, 0, stream>>>(XA, sc1, sh1, 32, (size_t)BATCH * 32);

    // G2: X1t[B,128] @ W2[128,256] -> X2 + stats2
    gemm_ld<128,256,256, 16,8, 256, 16, 128, true, false>
        <<<BATCH/128, 256, 0, stream>>>(XA, W2, b2, X2, sum2, sq2);
    finalize_bn<<<1, 256, 0, stream>>>(sum2, sq2, g2, be2, sc2, sh2, 256);
    bn_lrelu<<<2048, 256, 0, stream>>>(X2, sc2, sh2, 64, (size_t)BATCH * 64);

    // G3: X2t[B,256] @ W3[256,128] -> X3 + stats3
    gemm_ld<256,128,128, 16,8, 256, 16, 256, true, false>
        <<<BATCH/256, 256, 0, stream>>>(X2, W3, b3, XA, sum3, sq3);
    finalize_bn<<<1, 256, 0, stream>>>(sum3, sq3, g3, be3, sc3, sh3, 128);
    bn_lrelu<<<2048, 256, 0, stream>>>(XA, sc3, sh3, 32, (size_t)BATCH * 32);

    // G4: X3t[B,128] @ W4[128,25] -> logits (full-B prestage, no stats)
    gemm_ld<256,32,25, 4,8, 256, 16, 128, false, true>
        <<<BATCH/256, 256, 0, stream>>>(XA, W4, b4, logits, nullptr, nullptr);

    // P4: gumbel top-15 scan
    gumbel_topk<<<BATCH/256, 256, 0, stream>>>(logits, u, out);
}